// Round 7
// baseline (84.872 us; speedup 1.0000x reference)
//
#include <hip/hip_runtime.h>
#include <hip/hip_bf16.h>
#include <hip/hip_cooperative_groups.h>

#define B_SZ 4096
#define IN_D 256
#define OUT_D 256
#define NC 8

#define BM 64
#define BN 32
#define SSTEPS 16           // per wave: K = 2048/4 = 512 -> 16 steps of K=32

using f32x4 = __attribute__((ext_vector_type(4))) float;
using s16x8 = __attribute__((ext_vector_type(8))) short;

__device__ __forceinline__ unsigned short f2bf(float f) {
    union { float f; unsigned int u; } v; v.f = f;
    return (unsigned short)((v.u + 0x7fffu + ((v.u >> 16) & 1u)) >> 16);  // RNE
}

__device__ __forceinline__ float fast_tanh(float x) {
    float e = __expf(2.0f * x);   // saturates correctly at +-inf
    return 1.0f - 2.0f / (e + 1.0f);
}

// ---------------------------------------------------------------------------
// Single cooperative kernel. 512 blocks x 256 threads, all co-resident
// (LDS 36KB -> 4 blocks/CU capacity; we use 2/CU).
// Phase 1: per block, one 32b x 64i tanh-transpose tile -> tT[i][b] (f32),
//          plus a 128-wide W slice (i = bid>>1, o = (bid&1)*128 + tid).
// grid.sync()
// Phase 2: barrier-free GEMM (R6 body): 64x32 tile, 4-way K-split,
//          A-fragments as in-register power chains, W direct from L2.
// ---------------------------------------------------------------------------
__global__ __launch_bounds__(256) void kan_all(
    const float* __restrict__ x, const float* __restrict__ coefs,
    const float* __restrict__ alpha_at, const float* __restrict__ resid_scale,
    const float* __restrict__ spline_scale,
    float* __restrict__ tT, unsigned short* __restrict__ Wg,
    float* __restrict__ out)
{
    __shared__ float tt[32][65];                       // 8.3 KB (phase 1)
    __shared__ __align__(16) float lbuf[3][64 * 36];   // 27.6 KB (phase 2)

    const int tid = threadIdx.x;
    const int bid = blockIdx.x;

    // ---------------- Phase 1a: tanh + transpose (32b x 64i tile) ----------
    {
        const int b0 = (bid & 127) * 32;
        const int i0 = (bid >> 7) * 64;
        #pragma unroll
        for (int it = 0; it < 8; it++) {
            int e = it * 256 + tid;
            int r = e >> 6, c = e & 63;
            tt[r][c] = fast_tanh(x[(size_t)(b0 + r) * IN_D + i0 + c]);
        }
        __syncthreads();
        #pragma unroll
        for (int it = 0; it < 8; it++) {
            int e = it * 256 + tid;
            int ii = e >> 5, bb = e & 31;
            tT[(size_t)(i0 + ii) * B_SZ + b0 + bb] = tt[bb][ii];
        }
    }

    // ---------------- Phase 1b: W slice (i = bid>>1, 128 o's) --------------
    if (tid < 128) {
        const int i = bid >> 1;
        const int o = (bid & 1) * 128 + tid;

        float al = tanhf(alpha_at[0]);
        float mono[NC][NC];
        #pragma unroll
        for (int a = 0; a < NC; a++)
            #pragma unroll
            for (int b = 0; b < NC; b++) mono[a][b] = 0.f;
        mono[0][0] = 1.f;
        mono[1][1] = al + 1.f;
        #pragma unroll
        for (int n = 2; n < NC; n++) {
            float fn = (float)n;
            float c  = 2.f * fn + 2.f * al;
            float An = 2.f * fn * (fn + 2.f * al) * (c - 2.f);
            float Bn = (c - 1.f) * c * (c - 2.f);
            float Cn = 2.f * (fn + al - 1.f) * (fn + al - 1.f) * c;
            #pragma unroll
            for (int j = 0; j < NC; j++) {
                float tm = (j > 0 ? mono[n - 1][j - 1] : 0.f);
                mono[n][j] = (Bn * tm - Cn * mono[n - 2][j]) / An;
            }
        }

        float cf[NC];
        const float* cp = coefs + ((size_t)i * OUT_D + o) * NC;
        #pragma unroll
        for (int c = 0; c < NC; c++) cf[c] = cp[c];
        float ss = spline_scale[i * OUT_D + o];
        float rs = resid_scale[i];

        unsigned short w8[NC];
        #pragma unroll
        for (int j = 0; j < NC; j++) {
            float wv = 0.f;
            #pragma unroll
            for (int c = 0; c < NC; c++) wv += mono[c][j] * cf[c];
            wv *= ss * (1.0f / IN_D);
            if (j == 1) wv += rs * (1.0f / IN_D);
            w8[j] = f2bf(wv);
        }
        uint4 pk;
        unsigned int* pu = (unsigned int*)&pk;
        #pragma unroll
        for (int h = 0; h < 4; h++)
            pu[h] = (unsigned int)w8[2 * h] | ((unsigned int)w8[2 * h + 1] << 16);
        *(uint4*)(Wg + ((size_t)i * OUT_D + o) * NC) = pk;
    }

    // ---------------- grid-wide sync ---------------------------------------
    cooperative_groups::this_grid().sync();

    // ---------------- Phase 2: barrier-free GEMM ---------------------------
    const int lane = tid & 63;
    const int kg   = tid >> 6;          // wave = K-split index 0..3
    const int lr   = lane & 15;
    const int il   = lane >> 4;         // 0..3: feature-within-step

    // XCD-aware bijective swizzle (512 % 8 == 0); 64 mblk x 8 nblk
    const int swz  = (bid & 7) * 64 + (bid >> 3);
    const int mblk = swz >> 3, nblk = swz & 7;
    const int bm = mblk * BM, bn = nblk * BN;

    f32x4 acc[4][2];
    #pragma unroll
    for (int f = 0; f < 4; f++)
        #pragma unroll
        for (int g = 0; g < 2; g++)
            acc[f][g] = (f32x4){0.f, 0.f, 0.f, 0.f};

    #pragma unroll 4
    for (int s = 0; s < SSTEPS; ++s) {
        const int i0 = kg * 64 + s * 4 + il;     // this lane's feature index

        // W fragments: 16B/lane direct from global (L2-resident)
        uint4 bw[2];
        #pragma unroll
        for (int g = 0; g < 2; g++)
            bw[g] = *(const uint4*)(Wg + ((size_t)i0 * OUT_D + bn + g * 16 + lr) * 8);

        // A fragments: power chains in registers
        s16x8 af[4];
        #pragma unroll
        for (int f = 0; f < 4; f++) {
            float t = tT[(size_t)i0 * B_SZ + bm + f * 16 + lr];
            float p2 = t * t, p3 = p2 * t, p4 = p3 * t;
            float p5 = p4 * t, p6 = p5 * t, p7 = p6 * t;
            __hip_bfloat162 h0 = __float22bfloat162_rn(make_float2(1.0f, t));
            __hip_bfloat162 h1 = __float22bfloat162_rn(make_float2(p2, p3));
            __hip_bfloat162 h2 = __float22bfloat162_rn(make_float2(p4, p5));
            __hip_bfloat162 h3 = __float22bfloat162_rn(make_float2(p6, p7));
            uint4 pk;
            pk.x = *(unsigned int*)&h0;
            pk.y = *(unsigned int*)&h1;
            pk.z = *(unsigned int*)&h2;
            pk.w = *(unsigned int*)&h3;
            af[f] = *(s16x8*)&pk;
        }

        #pragma unroll
        for (int f = 0; f < 4; f++)
            #pragma unroll
            for (int g = 0; g < 2; g++)
                acc[f][g] = __builtin_amdgcn_mfma_f32_16x16x32_bf16(
                    af[f], *(s16x8*)&bw[g], acc[f][g], 0, 0, 0);
    }

    // ---- K-split reduction: waves 1..3 dump, wave 0 accumulates + stores
    if (kg > 0) {
        float* dst = &lbuf[kg - 1][lane * 36];
        #pragma unroll
        for (int f = 0; f < 4; f++)
            #pragma unroll
            for (int g = 0; g < 2; g++)
                *(f32x4*)(dst + f * 8 + g * 4) = acc[f][g];
    }
    __syncthreads();
    if (kg == 0) {
        #pragma unroll
        for (int r = 0; r < 3; r++) {
            const float* src = &lbuf[r][lane * 36];
            #pragma unroll
            for (int f = 0; f < 4; f++)
                #pragma unroll
                for (int g = 0; g < 2; g++)
                    acc[f][g] += *(const f32x4*)(src + f * 8 + g * 4);
        }
        // C/D layout: col = lane&15, row = (lane>>4)*4 + j
        #pragma unroll
        for (int f = 0; f < 4; f++)
            #pragma unroll
            for (int g = 0; g < 2; g++)
                #pragma unroll
                for (int j = 0; j < 4; j++) {
                    int r = bm + f * 16 + il * 4 + j;
                    int c = bn + g * 16 + lr;
                    out[(size_t)r * OUT_D + c] = acc[f][g][j];
                }
    }
}

extern "C" void kernel_launch(void* const* d_in, const int* in_sizes, int n_in,
                              void* d_out, int out_size, void* d_ws, size_t ws_size,
                              hipStream_t stream) {
    const float* x     = (const float*)d_in[0];
    const float* coefs = (const float*)d_in[1];
    const float* alpha = (const float*)d_in[2];
    const float* rs    = (const float*)d_in[3];
    const float* ss    = (const float*)d_in[4];
    float* out = (float*)d_out;

    unsigned short* Wg = (unsigned short*)d_ws;              // 1 MB
    float* tT = (float*)((char*)d_ws + (1 << 20));           // 4 MB

    void* args[] = {(void*)&x, (void*)&coefs, (void*)&alpha, (void*)&rs,
                    (void*)&ss, (void*)&tT, (void*)&Wg, (void*)&out};
    hipLaunchCooperativeKernel((const void*)kan_all, dim3(512), dim3(256),
                               args, 0, stream);
}

// Round 8
// 23.637 us; speedup vs baseline: 3.5907x; 3.5907x over previous
//
#include <hip/hip_runtime.h>
#include <hip/hip_bf16.h>

#define B_SZ 4096
#define IN_D 256
#define OUT_D 256
#define NC 8

#define BM 64
#define BN 32
#define SSTEPS 16           // per wave: K = 2048/4 = 512 -> 16 steps of K=32
#define TSTRIDE 68          // padded LDS row stride (floats) for tt

using f32x4 = __attribute__((ext_vector_type(4))) float;
using s16x8 = __attribute__((ext_vector_type(8))) short;

__device__ __forceinline__ unsigned short f2bf(float f) {
    union { float f; unsigned int u; } v; v.f = f;
    return (unsigned short)((v.u + 0x7fffu + ((v.u >> 16) & 1u)) >> 16);  // RNE
}

__device__ __forceinline__ float fast_tanh(float x) {
    float e = __expf(2.0f * x);   // saturates correctly at +-inf
    return 1.0f - 2.0f / (e + 1.0f);
}

// ---------------------------------------------------------------------------
// prep_w: W[(i*OUT+o)*8+j] = bf16((1/IN)*(ss[i,o]*sum_c mono[c][j]*cf[c]
//                                  + (j==1 ? rs[i] : 0)))   (256 blocks)
// ---------------------------------------------------------------------------
__global__ __launch_bounds__(256) void prep_w(
    const float* __restrict__ coefs, const float* __restrict__ alpha_at,
    const float* __restrict__ resid_scale, const float* __restrict__ spline_scale,
    unsigned short* __restrict__ Wg)
{
    const int i = blockIdx.x;
    const int o = threadIdx.x;

    float al = tanhf(alpha_at[0]);
    float mono[NC][NC];
    #pragma unroll
    for (int a = 0; a < NC; a++)
        #pragma unroll
        for (int b = 0; b < NC; b++) mono[a][b] = 0.f;
    mono[0][0] = 1.f;
    mono[1][1] = al + 1.f;
    #pragma unroll
    for (int n = 2; n < NC; n++) {
        float fn = (float)n;
        float c  = 2.f * fn + 2.f * al;
        float An = 2.f * fn * (fn + 2.f * al) * (c - 2.f);
        float Bn = (c - 1.f) * c * (c - 2.f);
        float Cn = 2.f * (fn + al - 1.f) * (fn + al - 1.f) * c;
        #pragma unroll
        for (int j = 0; j < NC; j++) {
            float tm = (j > 0 ? mono[n - 1][j - 1] : 0.f);
            mono[n][j] = (Bn * tm - Cn * mono[n - 2][j]) / An;
        }
    }

    float cf[NC];
    const float* cp = coefs + ((size_t)i * OUT_D + o) * NC;
    #pragma unroll
    for (int c = 0; c < NC; c++) cf[c] = cp[c];
    float ss = spline_scale[i * OUT_D + o];
    float rs = resid_scale[i];

    unsigned short w8[NC];
    #pragma unroll
    for (int j = 0; j < NC; j++) {
        float wv = 0.f;
        #pragma unroll
        for (int c = 0; c < NC; c++) wv += mono[c][j] * cf[c];
        wv *= ss * (1.0f / IN_D);
        if (j == 1) wv += rs * (1.0f / IN_D);
        w8[j] = f2bf(wv);
    }
    uint4 pk;
    unsigned int* pu = (unsigned int*)&pk;
    #pragma unroll
    for (int h = 0; h < 4; h++)
        pu[h] = (unsigned int)w8[2 * h] | ((unsigned int)w8[2 * h + 1] << 16);
    *(uint4*)(Wg + ((size_t)i * OUT_D + o) * NC) = pk;
}

// ---------------------------------------------------------------------------
// GEMM with in-kernel tanh. Block = 64x32 output tile, 4 waves = 4-way
// K-split. Prologue: stage tanh(x) for the whole 64-row x-panel into LDS,
// f-interleaved: tt[i][(m&15)*4 + (m>>4)] so each lane's per-step t-read is
// ONE ds_read_b128 (t for m = lr, lr+16, lr+32, lr+48). Main loop: zero
// barriers, zero global loads except 2 W-fragment uint4 per step (L2).
// A-fragments = in-register power chains. One LDS reduce at the end.
// ---------------------------------------------------------------------------
__global__ __launch_bounds__(256) void kan_gemm(
    const float* __restrict__ x, const unsigned short* __restrict__ Wg,
    float* __restrict__ out)
{
    __shared__ __align__(16) float smem[IN_D * TSTRIDE];   // 69.6 KB (tt / lbuf union)
    float* lbuf = smem;                                     // reused after main loop

    const int tid  = threadIdx.x;
    const int lane = tid & 63;
    const int kg   = tid >> 6;          // wave = K-split index 0..3
    const int lr   = lane & 15;
    const int il   = lane >> 4;         // 0..3: feature-within-step

    // XCD-aware bijective swizzle (512 % 8 == 0); 64 mblk x 8 nblk
    const int bid  = blockIdx.x;
    const int swz  = (bid & 7) * 64 + (bid >> 3);
    const int mblk = swz >> 3, nblk = swz & 7;
    const int bm = mblk * BM, bn = nblk * BN;

    // ---- Prologue: tanh panel -> LDS, f-interleaved --------------------
    // thread tid owns column i = tid; loads all 64 rows (coalesced across
    // lanes), tanh in-register, packs float4 {t[k],t[k+16],t[k+32],t[k+48]}
    // -> tt[i][4k..4k+3]  (index for row r is (r&15)*4 + (r>>4)).
    {
        const int i = tid;
        float t[64];
        #pragma unroll
        for (int r = 0; r < 64; r++)
            t[r] = fast_tanh(x[(size_t)(bm + r) * IN_D + i]);
        float* row = smem + i * TSTRIDE;
        #pragma unroll
        for (int k = 0; k < 16; k++) {
            f32x4 w4 = {t[k], t[k + 16], t[k + 32], t[k + 48]};
            *(f32x4*)(row + 4 * k) = w4;
        }
    }
    __syncthreads();

    f32x4 acc[4][2];
    #pragma unroll
    for (int f = 0; f < 4; f++)
        #pragma unroll
        for (int g = 0; g < 2; g++)
            acc[f][g] = (f32x4){0.f, 0.f, 0.f, 0.f};

    #pragma unroll
    for (int s = 0; s < SSTEPS; ++s) {
        const int i0 = kg * 64 + s * 4 + il;     // this lane's feature index

        // W fragments: 16B/lane direct from global (L2-resident)
        uint4 bw[2];
        #pragma unroll
        for (int g = 0; g < 2; g++)
            bw[g] = *(const uint4*)(Wg + ((size_t)i0 * OUT_D + bn + g * 16 + lr) * 8);

        // t for f=0..3 in one ds_read_b128
        f32x4 tv = *(const f32x4*)(smem + i0 * TSTRIDE + lr * 4);

        // A fragments: power chains in registers
        s16x8 af[4];
        #pragma unroll
        for (int f = 0; f < 4; f++) {
            float t = tv[f];
            float p2 = t * t, p3 = p2 * t, p4 = p3 * t;
            float p5 = p4 * t, p6 = p5 * t, p7 = p6 * t;
            __hip_bfloat162 h0 = __float22bfloat162_rn(make_float2(1.0f, t));
            __hip_bfloat162 h1 = __float22bfloat162_rn(make_float2(p2, p3));
            __hip_bfloat162 h2 = __float22bfloat162_rn(make_float2(p4, p5));
            __hip_bfloat162 h3 = __float22bfloat162_rn(make_float2(p6, p7));
            uint4 pk;
            pk.x = *(unsigned int*)&h0;
            pk.y = *(unsigned int*)&h1;
            pk.z = *(unsigned int*)&h2;
            pk.w = *(unsigned int*)&h3;
            af[f] = *(s16x8*)&pk;
        }

        #pragma unroll
        for (int f = 0; f < 4; f++)
            #pragma unroll
            for (int g = 0; g < 2; g++)
                acc[f][g] = __builtin_amdgcn_mfma_f32_16x16x32_bf16(
                    af[f], *(s16x8*)&bw[g], acc[f][g], 0, 0, 0);
    }

    // ---- K-split reduction: waves 1..3 dump, wave 0 accumulates + stores
    __syncthreads();                    // everyone done reading tt
    if (kg > 0) {
        float* dst = &lbuf[(kg - 1) * 64 * 36 + lane * 36];
        #pragma unroll
        for (int f = 0; f < 4; f++)
            #pragma unroll
            for (int g = 0; g < 2; g++)
                *(f32x4*)(dst + f * 8 + g * 4) = acc[f][g];
    }
    __syncthreads();
    if (kg == 0) {
        #pragma unroll
        for (int r = 0; r < 3; r++) {
            const float* src = &lbuf[r * 64 * 36 + lane * 36];
            #pragma unroll
            for (int f = 0; f < 4; f++)
                #pragma unroll
                for (int g = 0; g < 2; g++)
                    acc[f][g] += *(const f32x4*)(src + f * 8 + g * 4);
        }
        // C/D layout: col = lane&15, row = (lane>>4)*4 + j
        #pragma unroll
        for (int f = 0; f < 4; f++)
            #pragma unroll
            for (int g = 0; g < 2; g++)
                #pragma unroll
                for (int j = 0; j < 4; j++) {
                    int r = bm + f * 16 + il * 4 + j;
                    int c = bn + g * 16 + lr;
                    out[(size_t)r * OUT_D + c] = acc[f][g][j];
                }
    }
}

extern "C" void kernel_launch(void* const* d_in, const int* in_sizes, int n_in,
                              void* d_out, int out_size, void* d_ws, size_t ws_size,
                              hipStream_t stream) {
    const float* x     = (const float*)d_in[0];
    const float* coefs = (const float*)d_in[1];
    const float* alpha = (const float*)d_in[2];
    const float* rs    = (const float*)d_in[3];
    const float* ss    = (const float*)d_in[4];
    float* out = (float*)d_out;

    unsigned short* Wg = (unsigned short*)d_ws;   // 1 MB

    prep_w<<<dim3(IN_D), dim3(OUT_D), 0, stream>>>(coefs, alpha, rs, ss, Wg);
    kan_gemm<<<dim3((B_SZ / BM) * (OUT_D / BN)), dim3(256), 0, stream>>>(x, Wg, out);
}

// Round 10
// 19.934 us; speedup vs baseline: 4.2577x; 1.1858x over previous
//
#include <hip/hip_runtime.h>
#include <hip/hip_bf16.h>

#define B_SZ 4096
#define IN_D 256
#define OUT_D 256
#define NC 8

#define BM 64
#define BN 32
#define SSTEPS 16           // per wave: K = 2048/4 = 512 -> 16 steps of K=32

using f32x4 = __attribute__((ext_vector_type(4))) float;
using s16x8 = __attribute__((ext_vector_type(8))) short;

__device__ __forceinline__ unsigned short f2bf(float f) {
    union { float f; unsigned int u; } v; v.f = f;
    return (unsigned short)((v.u + 0x7fffu + ((v.u >> 16) & 1u)) >> 16);  // RNE
}

__device__ __forceinline__ float fast_tanh(float x) {
    float e = __expf(2.0f * x);   // saturates correctly at +-inf
    return 1.0f - 2.0f / (e + 1.0f);
}

// ---------------------------------------------------------------------------
// Fused prep, 512 blocks.
// Blocks [0,256): 64b x 64i tanh tile -> tTI interleaved:
//   tTI[i*B_SZ + G*64 + lr*4 + f] = tanh(x[G*64 + f*16 + lr, i])
//   (so a GEMM lane reads its 4 fragment-t's as ONE float4)
// Blocks [256,512): W[(i*OUT+o)*8+j] bf16 blocked, i = bid-256.
// ---------------------------------------------------------------------------
__global__ __launch_bounds__(256) void kan_prep(
    const float* __restrict__ x, const float* __restrict__ coefs,
    const float* __restrict__ alpha_at, const float* __restrict__ resid_scale,
    const float* __restrict__ spline_scale,
    float* __restrict__ tTI, unsigned short* __restrict__ Wg)
{
    const int tid = threadIdx.x;
    const int bid = blockIdx.x;

    if (bid < 256) {                     // ---- tanh + interleaved transpose
        __shared__ float tt[64][68];     // stride 68: read bank = (lr*4+ib)%32, 2-way = free
        const int b0 = (bid & 63) * 64;  // G = bid & 63
        const int i0 = (bid >> 6) * 64;
        #pragma unroll
        for (int it = 0; it < 16; it++) {
            int e = it * 256 + tid;
            int r = e >> 6, c = e & 63;
            tt[r][c] = fast_tanh(x[(size_t)(b0 + r) * IN_D + i0 + c]);
        }
        __syncthreads();
        const int lr = tid & 15;
        const int ib = tid >> 4;         // 0..15
        #pragma unroll
        for (int k = 0; k < 4; k++) {
            int i = ib + k * 16;         // 0..63
            f32x4 v = { tt[lr][i], tt[lr + 16][i], tt[lr + 32][i], tt[lr + 48][i] };
            *(f32x4*)(tTI + (size_t)(i0 + i) * B_SZ + b0 + lr * 4) = v;
        }
        return;
    }

    // ---- W prep (one feature i per block)
    const int i = bid - 256;
    const int o = tid;

    float al = tanhf(alpha_at[0]);
    float mono[NC][NC];
    #pragma unroll
    for (int a = 0; a < NC; a++)
        #pragma unroll
        for (int b = 0; b < NC; b++) mono[a][b] = 0.f;
    mono[0][0] = 1.f;
    mono[1][1] = al + 1.f;
    #pragma unroll
    for (int n = 2; n < NC; n++) {
        float fn = (float)n;
        float c  = 2.f * fn + 2.f * al;
        float An = 2.f * fn * (fn + 2.f * al) * (c - 2.f);
        float Bn = (c - 1.f) * c * (c - 2.f);
        float Cn = 2.f * (fn + al - 1.f) * (fn + al - 1.f) * c;
        #pragma unroll
        for (int j = 0; j < NC; j++) {
            float tm = (j > 0 ? mono[n - 1][j - 1] : 0.f);
            mono[n][j] = (Bn * tm - Cn * mono[n - 2][j]) / An;
        }
    }

    float cf[NC];
    const float* cp = coefs + ((size_t)i * OUT_D + o) * NC;
    #pragma unroll
    for (int c = 0; c < NC; c++) cf[c] = cp[c];
    float ss = spline_scale[i * OUT_D + o];
    float rs = resid_scale[i];

    unsigned short w8[NC];
    #pragma unroll
    for (int j = 0; j < NC; j++) {
        float wv = 0.f;
        #pragma unroll
        for (int c = 0; c < NC; c++) wv += mono[c][j] * cf[c];
        wv *= ss * (1.0f / IN_D);
        if (j == 1) wv += rs * (1.0f / IN_D);
        w8[j] = f2bf(wv);
    }
    uint4 pk;
    unsigned int* pu = (unsigned int*)&pk;
    #pragma unroll
    for (int h = 0; h < 4; h++)
        pu[h] = (unsigned int)w8[2 * h] | ((unsigned int)w8[2 * h + 1] << 16);
    *(uint4*)(Wg + ((size_t)i * OUT_D + o) * NC) = pk;
}

// ---------------------------------------------------------------------------
// Barrier-free GEMM. Block = 64x32 tile, 4 waves = 4-way K-split (K=512
// each, 16 steps FULLY UNROLLED). Per step per lane: ONE float4 tTI load +
// two uint4 W loads (all L2-resident, coalesced), power chains in registers,
// 8 MFMA (W fragments reused 4x). One LDS reduce at the end. 512 blocks.
// ---------------------------------------------------------------------------
__global__ __launch_bounds__(256) void kan_gemm(
    const float* __restrict__ tTI, const unsigned short* __restrict__ Wg,
    float* __restrict__ out)
{
    __shared__ __align__(16) float lbuf[3][64 * 36];   // 27.6 KB

    const int tid  = threadIdx.x;
    const int lane = tid & 63;
    const int kg   = tid >> 6;          // wave = K-split index 0..3
    const int lr   = lane & 15;
    const int il   = lane >> 4;         // 0..3: feature-within-step

    // XCD-aware bijective swizzle (512 % 8 == 0); 64 mblk x 8 nblk
    const int bid  = blockIdx.x;
    const int swz  = (bid & 7) * 64 + (bid >> 3);
    const int mblk = swz >> 3, nblk = swz & 7;
    const int bm = mblk * BM, bn = nblk * BN;

    f32x4 acc[4][2];
    #pragma unroll
    for (int f = 0; f < 4; f++)
        #pragma unroll
        for (int g = 0; g < 2; g++)
            acc[f][g] = (f32x4){0.f, 0.f, 0.f, 0.f};

    const float* tbase = tTI + bm + lr * 4;                     // + i0*B_SZ per step
    const unsigned short* wbase = Wg + ((size_t)bn + lr) * NC;  // + i0*OUT*NC

    #pragma unroll
    for (int s = 0; s < SSTEPS; ++s) {
        const int i0 = kg * 64 + s * 4 + il;     // this lane's feature index

        // W fragments: 16B/lane direct from global (L2-resident)
        uint4 bw[2];
        #pragma unroll
        for (int g = 0; g < 2; g++)
            bw[g] = *(const uint4*)(wbase + ((size_t)i0 * OUT_D + g * 16) * NC);

        // t for f=0..3 in ONE float4
        f32x4 tv = *(const f32x4*)(tbase + (size_t)i0 * B_SZ);

        // A fragments: power chains in registers
        s16x8 af[4];
        #pragma unroll
        for (int f = 0; f < 4; f++) {
            float t = tv[f];
            float p2 = t * t, p3 = p2 * t, p4 = p3 * t;
            float p5 = p4 * t, p6 = p5 * t, p7 = p6 * t;
            __hip_bfloat162 h0 = __float22bfloat162_rn(make_float2(1.0f, t));
            __hip_bfloat162 h1 = __float22bfloat162_rn(make_float2(p2, p3));
            __hip_bfloat162 h2 = __float22bfloat162_rn(make_float2(p4, p5));
            __hip_bfloat162 h3 = __float22bfloat162_rn(make_float2(p6, p7));
            uint4 pk;
            pk.x = *(unsigned int*)&h0;
            pk.y = *(unsigned int*)&h1;
            pk.z = *(unsigned int*)&h2;
            pk.w = *(unsigned int*)&h3;
            af[f] = *(s16x8*)&pk;
        }

        #pragma unroll
        for (int f = 0; f < 4; f++)
            #pragma unroll
            for (int g = 0; g < 2; g++)
                acc[f][g] = __builtin_amdgcn_mfma_f32_16x16x32_bf16(
                    af[f], *(s16x8*)&bw[g], acc[f][g], 0, 0, 0);
    }

    // ---- K-split reduction: waves 1..3 dump, wave 0 accumulates + stores
    if (kg > 0) {
        float* dst = &lbuf[kg - 1][lane * 36];
        #pragma unroll
        for (int f = 0; f < 4; f++)
            #pragma unroll
            for (int g = 0; g < 2; g++)
                *(f32x4*)(dst + f * 8 + g * 4) = acc[f][g];
    }
    __syncthreads();
    if (kg == 0) {
        #pragma unroll
        for (int r = 0; r < 3; r++) {
            const float* src = &lbuf[r][lane * 36];
            #pragma unroll
            for (int f = 0; f < 4; f++)
                #pragma unroll
                for (int g = 0; g < 2; g++)
                    acc[f][g] += *(const f32x4*)(src + f * 8 + g * 4);
        }
        // C/D layout: col = lane&15, row = (lane>>4)*4 + j
        #pragma unroll
        for (int f = 0; f < 4; f++)
            #pragma unroll
            for (int g = 0; g < 2; g++)
                #pragma unroll
                for (int j = 0; j < 4; j++) {
                    int r = bm + f * 16 + il * 4 + j;
                    int c = bn + g * 16 + lr;
                    out[(size_t)r * OUT_D + c] = acc[f][g][j];
                }
    }
}

extern "C" void kernel_launch(void* const* d_in, const int* in_sizes, int n_in,
                              void* d_out, int out_size, void* d_ws, size_t ws_size,
                              hipStream_t stream) {
    const float* x     = (const float*)d_in[0];
    const float* coefs = (const float*)d_in[1];
    const float* alpha = (const float*)d_in[2];
    const float* rs    = (const float*)d_in[3];
    const float* ss    = (const float*)d_in[4];
    float* out = (float*)d_out;

    unsigned short* Wg = (unsigned short*)d_ws;              // 1 MB
    float* tTI = (float*)((char*)d_ws + (1 << 20));          // 4 MB

    kan_prep<<<dim3(512), dim3(256), 0, stream>>>(x, coefs, alpha, rs, ss, tTI, Wg);
    kan_gemm<<<dim3((B_SZ / BM) * (OUT_D / BN)), dim3(256), 0, stream>>>(tTI, Wg, out);
}